// Round 6
// baseline (425.964 us; speedup 1.0000x reference)
//
#include <hip/hip_runtime.h>

// ContextCompressor: scores = hidden·query (B,T), top-k=T/2 per row,
// indices sorted ascending, mask (B,T) as 0/1 floats, gather rows.
// Phase 1: score_kernel  — wave-per-token fp32 dot, float4 loads.
// Phase 2: select_kernel — per-batch LDS radix-select (exact k, stable ties,
//                          parallel suffix-sum bin pick) + block scans
//                          -> ascending indices + mask.
// Phase 3: gather_kernel — block-per-row float4 copy.

__global__ __launch_bounds__(256) void score_kernel(
    const float* __restrict__ hidden, const float* __restrict__ query,
    float* __restrict__ scores, int D4)
{
    // one wave (64 lanes) per token; 4 waves per block
    int token = blockIdx.x * 4 + (threadIdx.x >> 6);
    int lane  = threadIdx.x & 63;
    const float4* row = reinterpret_cast<const float4*>(hidden) + (size_t)token * D4;
    const float4* q4  = reinterpret_cast<const float4*>(query);
    float acc = 0.f;
#pragma unroll
    for (int i = 0; i < 4; ++i) {           // 4*64 = 256 float4 = 1024 floats
        float4 h = row[lane + i * 64];
        float4 q = q4[lane + i * 64];
        acc = fmaf(h.x, q.x, acc);
        acc = fmaf(h.y, q.y, acc);
        acc = fmaf(h.z, q.z, acc);
        acc = fmaf(h.w, q.w, acc);
    }
#pragma unroll
    for (int off = 32; off > 0; off >>= 1)
        acc += __shfl_down(acc, off, 64);
    if (lane == 0) scores[token] = acc;
}

// exclusive block scan over 1024 threads (16 waves); wsum has 16 slots
__device__ __forceinline__ int block_excl_scan_1024(int val, int tid, int* wsum)
{
    int lane = tid & 63;
    int wid  = tid >> 6;
    int v = val;
#pragma unroll
    for (int d = 1; d < 64; d <<= 1) {
        int u = __shfl_up(v, d, 64);
        if (lane >= d) v += u;
    }
    if (lane == 63) wsum[wid] = v;          // inclusive wave sum
    __syncthreads();
    if (tid < 64) {
        int orig = (lane < 16) ? wsum[lane] : 0;
        int w = orig;
#pragma unroll
        for (int d = 1; d < 16; d <<= 1) {
            int u = __shfl_up(w, d, 64);
            if (lane >= d) w += u;
        }
        if (lane < 16) wsum[lane] = w - orig;   // exclusive wave offsets
    }
    __syncthreads();
    int res = wsum[wid] + (v - val);        // wave offset + excl-within-wave
    __syncthreads();                        // protect wsum for next call
    return res;
}

__global__ __launch_bounds__(1024) void select_kernel(
    const float* __restrict__ scores, int* __restrict__ indices,
    float* __restrict__ maskf, int T, int k)
{
    __shared__ unsigned keys[8192];
    __shared__ int hist[256];
    __shared__ int bcast[2];
    __shared__ int wsum[16];

    int tid  = threadIdx.x;
    int lane = tid & 63;
    int wid  = tid >> 6;
    int b    = blockIdx.x;
    const float* srow = scores + (size_t)b * T;

    // load scores, flip to order-preserving unsigned keys
    for (int i = tid; i < T; i += 1024) {
        unsigned u = __float_as_uint(srow[i]);
        keys[i] = (u & 0x80000000u) ? ~u : (u | 0x80000000u);
    }
    __syncthreads();

    // radix-select the k-th largest key (8 bits per pass, high->low).
    // Bin pick is PARALLEL: suffix-sum over reversed bins via 4-wave scan
    // (a serial tid==0 scan = up to 256 dependent ~120cy LDS reads/pass).
    unsigned prefix = 0u, pmask = 0u;
    int remaining = k;
    for (int shift = 24; shift >= 0; shift -= 8) {
        if (tid < 256) hist[tid] = 0;
        __syncthreads();
        for (int i = tid; i < T; i += 1024) {
            unsigned kk = keys[i];
            if ((kk & pmask) == prefix)
                atomicAdd(&hist[(kk >> shift) & 255u], 1);
        }
        __syncthreads();

        // incl[tid] = sum_{j<=tid} hist[255-j]  (count of keys in bins >= 255-tid)
        int val = 0, v = 0;
        if (tid < 256) {
            val = hist[255 - tid];
            v = val;
#pragma unroll
            for (int d = 1; d < 64; d <<= 1) {
                int u = __shfl_up(v, d, 64);
                if (lane >= d) v += u;
            }
            if (lane == 63) wsum[wid] = v;      // wid 0..3
        }
        __syncthreads();
        if (tid < 64) {
            int orig = (lane < 4) ? wsum[lane] : 0;
            int w = orig;
#pragma unroll
            for (int d = 1; d < 4; d <<= 1) {
                int u = __shfl_up(w, d, 64);
                if (lane >= d) w += u;
            }
            if (lane < 4) wsum[lane] = w - orig;    // exclusive wave offsets
        }
        __syncthreads();
        if (tid < 256) {
            int incl   = v + wsum[wid];     // keys in bins >= bb
            int strict = incl - val;        // keys in bins >  bb
            if (strict < remaining && incl >= remaining) {
                bcast[0] = 255 - tid;               // selected bin (exactly one hits)
                bcast[1] = remaining - strict;      // ties to take in this bin
            }
        }
        __syncthreads();
        prefix |= ((unsigned)bcast[0]) << shift;
        pmask  |= (255u << shift);
        remaining = bcast[1];
        __syncthreads();
    }
    unsigned thr = prefix;        // k-th largest key value
    int ntie_take = remaining;    // ties at thr to take (lowest indices first)

    // each thread owns 8 consecutive tokens
    int base = tid * 8;
    int gtflag[8], tieflag[8];
    int tiecnt = 0;
#pragma unroll
    for (int j = 0; j < 8; ++j) {
        unsigned kk = keys[base + j];
        gtflag[j]  = (kk > thr) ? 1 : 0;
        tieflag[j] = (kk == thr) ? 1 : 0;
        tiecnt += tieflag[j];
    }
    int tie_excl = block_excl_scan_1024(tiecnt, tid, wsum);

    int selflag[8];
    int selcnt = 0;
    {
        int r = tie_excl;
#pragma unroll
        for (int j = 0; j < 8; ++j) {
            int take = gtflag[j] | (tieflag[j] & ((r < ntie_take) ? 1 : 0));
            r += tieflag[j];
            selflag[j] = take;
            selcnt += take;
        }
    }
    int pos = block_excl_scan_1024(selcnt, tid, wsum);

    // vectorized mask store: 8 consecutive floats -> 2x float4
    {
        float4 m0 = make_float4(selflag[0] ? 1.f : 0.f, selflag[1] ? 1.f : 0.f,
                                selflag[2] ? 1.f : 0.f, selflag[3] ? 1.f : 0.f);
        float4 m1 = make_float4(selflag[4] ? 1.f : 0.f, selflag[5] ? 1.f : 0.f,
                                selflag[6] ? 1.f : 0.f, selflag[7] ? 1.f : 0.f);
        float4* mrow = reinterpret_cast<float4*>(maskf + (size_t)b * T + base);
        mrow[0] = m0;
        mrow[1] = m1;
    }
#pragma unroll
    for (int j = 0; j < 8; ++j) {
        if (selflag[j]) indices[(size_t)b * k + pos] = base + j;
        pos += selflag[j];
    }
}

__global__ __launch_bounds__(256) void gather_kernel(
    const float* __restrict__ hidden, const int* __restrict__ indices,
    float* __restrict__ out, int T, int k, int D4)
{
    int row = blockIdx.x;               // 0 .. B*k-1
    int b   = row / k;
    size_t srcrow = (size_t)b * T + indices[row];
    const float4* src = reinterpret_cast<const float4*>(hidden) + srcrow * D4;
    float4*       dst = reinterpret_cast<float4*>(out) + (size_t)row * D4;
    dst[threadIdx.x] = src[threadIdx.x];   // 256 threads * 16B = 4 KiB = one row
}

extern "C" void kernel_launch(void* const* d_in, const int* in_sizes, int n_in,
                              void* d_out, int out_size, void* d_ws, size_t ws_size,
                              hipStream_t stream)
{
    const float* hidden = (const float*)d_in[0];
    const float* query  = (const float*)d_in[1];

    int D  = in_sizes[1];          // 1024
    int BT = in_sizes[0] / D;      // B*T = 65536
    const int T = 8192;
    int B  = BT / T;               // 8
    int k  = T / 2;                // TARGET_RATIO = 0.5
    if (k < 64) k = 64;            // MIN_TOKENS
    if (k > T)  k = T;
    int D4 = D / 4;

    float* scores  = (float*)d_ws;
    int*   indices = (int*)((char*)d_ws + (size_t)BT * sizeof(float));
    float* outc    = (float*)d_out;
    float* maskf   = outc + (size_t)B * k * D;   // mask appended after compressed

    score_kernel<<<BT / 4, 256, 0, stream>>>(hidden, query, scores, D4);
    select_kernel<<<B, 1024, 0, stream>>>(scores, indices, maskf, T, k);
    gather_kernel<<<B * k, 256, 0, stream>>>(hidden, indices, outc, T, k, D4);
}

// Round 14
// 424.432 us; speedup vs baseline: 1.0036x; 1.0036x over previous
//
#include <hip/hip_runtime.h>

// ContextCompressor: scores = hidden·query (B,T), top-k=T/2 per row,
// indices sorted ascending, mask (B,T) as 0/1 floats, gather rows.
// R8: same as R7 but nontemporal stores go through a native ext_vector_type
//     (clang rejects HIP_vector_type float4 for __builtin_nontemporal_store).

typedef float nfloat4 __attribute__((ext_vector_type(4)));

__global__ __launch_bounds__(256) void score_kernel(
    const float* __restrict__ hidden, const float* __restrict__ query,
    float* __restrict__ scores, int D4)
{
    // one wave (64 lanes) per TWO consecutive tokens; 4 waves per block
    int wave = blockIdx.x * 4 + (threadIdx.x >> 6);
    int lane = threadIdx.x & 63;
    int t0   = wave * 2;
    const float4* r0 = reinterpret_cast<const float4*>(hidden) + (size_t)t0 * D4;
    const float4* r1 = r0 + D4;
    const float4* q4 = reinterpret_cast<const float4*>(query);
    float a0 = 0.f, a1 = 0.f;
#pragma unroll
    for (int i = 0; i < 4; ++i) {           // 4*64 = 256 float4 = 1024 floats/row
        float4 q  = q4[lane + i * 64];      // L1-resident broadcast
        float4 h0 = r0[lane + i * 64];
        float4 h1 = r1[lane + i * 64];
        a0 = fmaf(h0.x, q.x, a0); a0 = fmaf(h0.y, q.y, a0);
        a0 = fmaf(h0.z, q.z, a0); a0 = fmaf(h0.w, q.w, a0);
        a1 = fmaf(h1.x, q.x, a1); a1 = fmaf(h1.y, q.y, a1);
        a1 = fmaf(h1.z, q.z, a1); a1 = fmaf(h1.w, q.w, a1);
    }
#pragma unroll
    for (int off = 32; off > 0; off >>= 1) {    // two independent chains
        a0 += __shfl_down(a0, off, 64);
        a1 += __shfl_down(a1, off, 64);
    }
    if (lane == 0) { scores[t0] = a0; scores[t0 + 1] = a1; }
}

// exclusive block scan over 1024 threads (16 waves); wsum has 16 slots
__device__ __forceinline__ int block_excl_scan_1024(int val, int tid, int* wsum)
{
    int lane = tid & 63;
    int wid  = tid >> 6;
    int v = val;
#pragma unroll
    for (int d = 1; d < 64; d <<= 1) {
        int u = __shfl_up(v, d, 64);
        if (lane >= d) v += u;
    }
    if (lane == 63) wsum[wid] = v;          // inclusive wave sum
    __syncthreads();
    if (tid < 64) {
        int orig = (lane < 16) ? wsum[lane] : 0;
        int w = orig;
#pragma unroll
        for (int d = 1; d < 16; d <<= 1) {
            int u = __shfl_up(w, d, 64);
            if (lane >= d) w += u;
        }
        if (lane < 16) wsum[lane] = w - orig;   // exclusive wave offsets
    }
    __syncthreads();
    int res = wsum[wid] + (v - val);        // wave offset + excl-within-wave
    __syncthreads();                        // protect wsum for next call
    return res;
}

__global__ __launch_bounds__(1024) void select_kernel(
    const float* __restrict__ scores, int* __restrict__ indices,
    float* __restrict__ maskf, int T, int k)
{
    __shared__ unsigned keys[8192];
    __shared__ int hist[256];
    __shared__ int bcast[2];
    __shared__ int wsum[16];

    int tid  = threadIdx.x;
    int lane = tid & 63;
    int wid  = tid >> 6;
    int b    = blockIdx.x;
    const float* srow = scores + (size_t)b * T;

    // load scores, flip to order-preserving unsigned keys
    for (int i = tid; i < T; i += 1024) {
        unsigned u = __float_as_uint(srow[i]);
        keys[i] = (u & 0x80000000u) ? ~u : (u | 0x80000000u);
    }
    __syncthreads();

    // radix-select the k-th largest key (8 bits per pass, high->low).
    // Bin pick is PARALLEL: suffix-sum over reversed bins via 4-wave scan.
    unsigned prefix = 0u, pmask = 0u;
    int remaining = k;
    for (int shift = 24; shift >= 0; shift -= 8) {
        if (tid < 256) hist[tid] = 0;
        __syncthreads();
        for (int i = tid; i < T; i += 1024) {
            unsigned kk = keys[i];
            if ((kk & pmask) == prefix)
                atomicAdd(&hist[(kk >> shift) & 255u], 1);
        }
        __syncthreads();

        // incl[tid] = sum_{j<=tid} hist[255-j]  (count of keys in bins >= 255-tid)
        int val = 0, v = 0;
        if (tid < 256) {
            val = hist[255 - tid];
            v = val;
#pragma unroll
            for (int d = 1; d < 64; d <<= 1) {
                int u = __shfl_up(v, d, 64);
                if (lane >= d) v += u;
            }
            if (lane == 63) wsum[wid] = v;      // wid 0..3
        }
        __syncthreads();
        if (tid < 64) {
            int orig = (lane < 4) ? wsum[lane] : 0;
            int w = orig;
#pragma unroll
            for (int d = 1; d < 4; d <<= 1) {
                int u = __shfl_up(w, d, 64);
                if (lane >= d) w += u;
            }
            if (lane < 4) wsum[lane] = w - orig;    // exclusive wave offsets
        }
        __syncthreads();
        if (tid < 256) {
            int incl   = v + wsum[wid];     // keys in bins >= bb
            int strict = incl - val;        // keys in bins >  bb
            if (strict < remaining && incl >= remaining) {
                bcast[0] = 255 - tid;               // selected bin (exactly one hits)
                bcast[1] = remaining - strict;      // ties to take in this bin
            }
        }
        __syncthreads();
        prefix |= ((unsigned)bcast[0]) << shift;
        pmask  |= (255u << shift);
        remaining = bcast[1];
        __syncthreads();
    }
    unsigned thr = prefix;        // k-th largest key value
    int ntie_take = remaining;    // ties at thr to take (lowest indices first)

    // each thread owns 8 consecutive tokens
    int base = tid * 8;
    int gtflag[8], tieflag[8];
    int tiecnt = 0;
#pragma unroll
    for (int j = 0; j < 8; ++j) {
        unsigned kk = keys[base + j];
        gtflag[j]  = (kk > thr) ? 1 : 0;
        tieflag[j] = (kk == thr) ? 1 : 0;
        tiecnt += tieflag[j];
    }
    int tie_excl = block_excl_scan_1024(tiecnt, tid, wsum);

    int selflag[8];
    int selcnt = 0;
    {
        int r = tie_excl;
#pragma unroll
        for (int j = 0; j < 8; ++j) {
            int take = gtflag[j] | (tieflag[j] & ((r < ntie_take) ? 1 : 0));
            r += tieflag[j];
            selflag[j] = take;
            selcnt += take;
        }
    }
    int pos = block_excl_scan_1024(selcnt, tid, wsum);

    // vectorized mask store: 8 consecutive floats -> 2x float4
    {
        float4 m0 = make_float4(selflag[0] ? 1.f : 0.f, selflag[1] ? 1.f : 0.f,
                                selflag[2] ? 1.f : 0.f, selflag[3] ? 1.f : 0.f);
        float4 m1 = make_float4(selflag[4] ? 1.f : 0.f, selflag[5] ? 1.f : 0.f,
                                selflag[6] ? 1.f : 0.f, selflag[7] ? 1.f : 0.f);
        float4* mrow = reinterpret_cast<float4*>(maskf + (size_t)b * T + base);
        mrow[0] = m0;
        mrow[1] = m1;
    }
#pragma unroll
    for (int j = 0; j < 8; ++j) {
        if (selflag[j]) indices[(size_t)b * k + pos] = base + j;
        pos += selflag[j];
    }
}

__global__ __launch_bounds__(256) void gather_kernel(
    const float* __restrict__ hidden, const int* __restrict__ indices,
    float* __restrict__ out, int T, int k, int D4)
{
    // one wave per output row, 4 rows per block
    int row  = blockIdx.x * 4 + (threadIdx.x >> 6);     // 0 .. B*k-1
    int lane = threadIdx.x & 63;
    int b    = row / k;
    int t    = indices[row];                            // wave-uniform broadcast
    const nfloat4* src = reinterpret_cast<const nfloat4*>(hidden) + ((size_t)b * T + t) * D4;
    nfloat4*       dst = reinterpret_cast<nfloat4*>(out) + (size_t)row * D4;
#pragma unroll
    for (int i = 0; i < 4; ++i) {   // 4 x (64 lanes x 16B) = 4 KiB row
        nfloat4 v = src[lane + i * 64];
        __builtin_nontemporal_store(v, &dst[lane + i * 64]);
    }
}

extern "C" void kernel_launch(void* const* d_in, const int* in_sizes, int n_in,
                              void* d_out, int out_size, void* d_ws, size_t ws_size,
                              hipStream_t stream)
{
    const float* hidden = (const float*)d_in[0];
    const float* query  = (const float*)d_in[1];

    int D  = in_sizes[1];          // 1024
    int BT = in_sizes[0] / D;      // B*T = 65536
    const int T = 8192;
    int B  = BT / T;               // 8
    int k  = T / 2;                // TARGET_RATIO = 0.5
    if (k < 64) k = 64;            // MIN_TOKENS
    if (k > T)  k = T;
    int D4 = D / 4;

    float* scores  = (float*)d_ws;
    int*   indices = (int*)((char*)d_ws + (size_t)BT * sizeof(float));
    float* outc    = (float*)d_out;
    float* maskf   = outc + (size_t)B * k * D;   // mask appended after compressed

    score_kernel<<<BT / 8, 256, 0, stream>>>(hidden, query, scores, D4);
    select_kernel<<<B, 1024, 0, stream>>>(scores, indices, maskf, T, k);
    gather_kernel<<<(B * k) / 4, 256, 0, stream>>>(hidden, indices, outc, T, k, D4);
}